// Round 2
// baseline (200.281 us; speedup 1.0000x reference)
//
#include <hip/hip_runtime.h>
#include <hip/hip_bf16.h>
#include <stdint.h>

// MixAttention: B=4, L=2048, D=512, H=8, A=64
// ws layout (bytes):
//  wt   @ 0         : 6*512*512*2   = 3145728   (W^T bf16, [mat][out][in])
//  xb   @ 3145728   : 5*8192*512*2  = 41943040  (inputs bf16)
//  qws  @ 45088768  : 32*2048*128*2 = 16777216  (Q' = [qd|qt]/8, [bh][l][128])
//  kws  @ 61865984  : 16777216                  (K' = [kd|kt], [bh][l][128])
//  vws  @ 78643200  : 32*64*2048*2  = 8388608   (V^T, [bh][a][l])
//  ctxb @ 87031808  : 8192*512*2    = 8388608   (attn out, [row][512])
//  total 95420416

using f32x4  = __attribute__((ext_vector_type(4))) float;
using bf16x8 = __attribute__((ext_vector_type(8))) short;

typedef __attribute__((address_space(1))) const uint32_t g_u32;
typedef __attribute__((address_space(3))) uint32_t l_u32;

#if __has_builtin(__builtin_amdgcn_exp2f)
#define EXP2F __builtin_amdgcn_exp2f
#else
#define EXP2F exp2f
#endif
#define LOG2E 1.44269504f

__device__ __forceinline__ void glds16(const void* g, void* l) {
  __builtin_amdgcn_global_load_lds((g_u32*)g, (l_u32*)l, 16, 0, 0);
}

__device__ __forceinline__ unsigned short f2bfu(float f) {
  __hip_bfloat16 h = __float2bfloat16(f);
  union { __hip_bfloat16 h; unsigned short u; } v;
  v.h = h;
  return v.u;
}

// ---------------- K0a: W [512 in][512 out] f32 -> W^T [out][in] bf16 ----------------
__global__ __launch_bounds__(256) void k_prep_w(
    const float* __restrict__ w0, const float* __restrict__ w1,
    const float* __restrict__ w2, const float* __restrict__ w3,
    const float* __restrict__ w4, const float* __restrict__ w5,
    unsigned short* __restrict__ wt) {
  __shared__ float tile[64][68];
  const float* wsrc[6] = {w0, w1, w2, w3, w4, w5};
  int bid = blockIdx.x;
  int mat = bid >> 6, tid = bid & 63;
  int k0 = (tid >> 3) << 6, c0 = (tid & 7) << 6;
  const float* w = wsrc[mat];
  int t = threadIdx.x;
  {
    int r = t >> 2, cq = (t & 3) << 4;
    const float4* src = reinterpret_cast<const float4*>(w + (size_t)(k0 + r) * 512 + c0 + cq);
#pragma unroll
    for (int j = 0; j < 4; ++j) {
      float4 v = src[j];
      tile[r][cq + j * 4 + 0] = v.x;
      tile[r][cq + j * 4 + 1] = v.y;
      tile[r][cq + j * 4 + 2] = v.z;
      tile[r][cq + j * 4 + 3] = v.w;
    }
  }
  __syncthreads();
  {
    int cc = t >> 2, kq = (t & 3) << 4;
    union { unsigned short u[16]; uint4 v[2]; } p;
#pragma unroll
    for (int j = 0; j < 16; ++j) p.u[j] = f2bfu(tile[kq + j][cc]);
    unsigned short* dst = wt + (size_t)mat * 262144 + (size_t)(c0 + cc) * 512 + k0 + kq;
    *reinterpret_cast<uint4*>(dst)     = p.v[0];
    *reinterpret_cast<uint4*>(dst + 8) = p.v[1];
  }
}

// ---------------- K0b: X f32 -> bf16 ----------------
__global__ __launch_bounds__(256) void k_cvt_x(
    const float* __restrict__ x0, const float* __restrict__ x1,
    const float* __restrict__ x2, const float* __restrict__ x3,
    const float* __restrict__ x4, unsigned short* __restrict__ xb) {
  const float* xs[5] = {x0, x1, x2, x3, x4};
  int blk = blockIdx.x;
  int which = blk >> 11;
  size_t off = ((size_t)(blk & 2047) * 256 + threadIdx.x) * 8;
  const float* x = xs[which] + off;
  float4 a = reinterpret_cast<const float4*>(x)[0];
  float4 b = reinterpret_cast<const float4*>(x)[1];
  union { unsigned short u[8]; uint4 v; } p;
  p.u[0] = f2bfu(a.x); p.u[1] = f2bfu(a.y); p.u[2] = f2bfu(a.z); p.u[3] = f2bfu(a.w);
  p.u[4] = f2bfu(b.x); p.u[5] = f2bfu(b.y); p.u[6] = f2bfu(b.z); p.u[7] = f2bfu(b.w);
  *reinterpret_cast<uint4*>(xb + (size_t)which * 4194304 + off) = p.v;
}

// ---------------- shared GEMM core: 64x64 tile, BK=64, 4 waves ----------------
// A [64 rows][512] bf16 row-major slab, B = W^T [64 cols][512] bf16 slab.
// acc[ct] covers rows (w*16 + g*4 + r), cols (ct*16 + lane&15) -- C-layout verified.
__device__ __forceinline__ void gemm_core(
    const unsigned short* Ag, const unsigned short* Wg,
    unsigned short* Al, unsigned short* Bl, f32x4 acc[4]) {
  int t = threadIdx.x;
  int lane = t & 63, w = t >> 6, g = lane >> 4, c = lane & 15;
#pragma unroll 1
  for (int it = 0; it < 8; ++it) {
    __syncthreads();
#pragma unroll
    for (int j = 0; j < 2; ++j) {
      int cid = t + j * 256;
      int row = cid >> 3, ch = cid & 7;
      // source pre-swizzled so linear LDS dest + swizzled read = identity
      glds16(Ag + (size_t)row * 512 + it * 64 + ((ch ^ (row & 7)) << 3), Al + cid * 8);
      glds16(Wg + (size_t)row * 512 + it * 64 + ((ch ^ (row & 7)) << 3), Bl + cid * 8);
    }
    __syncthreads();
#pragma unroll
    for (int fi = 0; fi < 2; ++fi) {
      int arow = w * 16 + c;
      bf16x8 af = *reinterpret_cast<const bf16x8*>(
          Al + arow * 64 + (((fi * 4 + g) ^ (arow & 7)) << 3));
#pragma unroll
      for (int ct = 0; ct < 4; ++ct) {
        int brow = ct * 16 + c;
        bf16x8 bf = *reinterpret_cast<const bf16x8*>(
            Bl + brow * 64 + (((fi * 4 + g) ^ (brow & 7)) << 3));
        acc[ct] = __builtin_amdgcn_mfma_f32_16x16x32_bf16(af, bf, acc[ct], 0, 0, 0);
      }
    }
  }
}

// ---------------- K1: 5 projections -> Q'/K'/V^T bf16 ----------------
__global__ __launch_bounds__(256) void k_proj(
    const unsigned short* __restrict__ xb, const unsigned short* __restrict__ wt,
    const float* __restrict__ b0, const float* __restrict__ b1,
    const float* __restrict__ b2, const float* __restrict__ b3,
    const float* __restrict__ b4,
    unsigned short* __restrict__ qws, unsigned short* __restrict__ kws,
    unsigned short* __restrict__ vws) {
  __shared__ __align__(16) unsigned short Al[4096];
  __shared__ __align__(16) unsigned short Bl[4096];
  int bid = blockIdx.x;
  int proj = bid >> 10, rem = bid & 1023;
  int rb = rem >> 3, cb = rem & 7;  // cb == head h (BN=64 == A)
  const unsigned short* Ag = xb + (size_t)proj * 4194304 + (size_t)rb * 64 * 512;
  const unsigned short* Wg = wt + (size_t)proj * 262144 + (size_t)cb * 64 * 512;
  f32x4 acc[4];
#pragma unroll
  for (int i = 0; i < 4; ++i) acc[i] = f32x4{0.f, 0.f, 0.f, 0.f};
  gemm_core(Ag, Wg, Al, Bl, acc);

  const float* bias_arr[5] = {b0, b1, b2, b3, b4};
  const float* bias = bias_arr[proj];
  float scale = (proj < 2) ? 0.125f : 1.0f;  // fold 1/sqrt(A) into Q'
  int lane = threadIdx.x & 63, w = threadIdx.x >> 6, g = lane >> 4, c = lane & 15;
  int rowbase = rb * 64 + w * 16 + g * 4;
  unsigned short* qkdst = (proj < 2) ? qws : kws;
  int half = (proj & 1) ? 64 : 0;
#pragma unroll
  for (int ct = 0; ct < 4; ++ct) {
    int n = cb * 64 + ct * 16 + c;
    float bv = bias[n];
#pragma unroll
    for (int r = 0; r < 4; ++r) {
      float v = (acc[ct][r] + bv) * scale;
      unsigned short u = f2bfu(v);
      int rowg = rowbase + r;
      int b = rowg >> 11, l = rowg & 2047;
      if (proj < 4) {
        size_t di = ((size_t)(b * 8 + cb) * 2048 + l) * 128 + half + ct * 16 + c;
        qkdst[di] = u;
      } else {
        size_t di = ((size_t)(b * 8 + cb) * 64 + ct * 16 + c) * 2048 + l;
        vws[di] = u;
      }
    }
  }
}

// ---------------- K2: flash attention, head-dim 128 QK / 64 V ----------------
__global__ __launch_bounds__(256) void k_attn(
    const unsigned short* __restrict__ qws, const unsigned short* __restrict__ kws,
    const unsigned short* __restrict__ vws, unsigned short* __restrict__ ctxb) {
  __shared__ __align__(16) unsigned short Kl[8192];     // [64 k][128 f] swizzled
  __shared__ __align__(16) unsigned short Vl[4096];     // [64 a][64 k]  swizzled
  __shared__ __align__(16) unsigned short Pl[4][1152];  // per-wave [16 q][72] (144B pitch)
  int bid = blockIdx.x;
  int bh = bid >> 5, qb = bid & 31;
  int t = threadIdx.x;
  int w = t >> 6, lane = t & 63, g = lane >> 4, c = lane & 15;

  const unsigned short* Qg = qws + ((size_t)bh * 2048 + qb * 64 + w * 16 + c) * 128;
  bf16x8 qf[4];
#pragma unroll
  for (int fi = 0; fi < 4; ++fi)
    qf[fi] = *reinterpret_cast<const bf16x8*>(Qg + fi * 32 + g * 8);

  f32x4 acc[4];
#pragma unroll
  for (int i = 0; i < 4; ++i) acc[i] = f32x4{0.f, 0.f, 0.f, 0.f};
  float m = -1e30f, lsum = 0.f;
  const unsigned short* Kg = kws + (size_t)bh * 2048 * 128;
  const unsigned short* Vg = vws + (size_t)bh * 64 * 2048;
  unsigned short* Pw = &Pl[w][0];

#pragma unroll 1
  for (int it = 0; it < 32; ++it) {
    __syncthreads();
#pragma unroll
    for (int j = 0; j < 4; ++j) {
      int cid = t + j * 256;
      int row = cid >> 4, ch = cid & 15;
      glds16(Kg + ((size_t)it * 64 + row) * 128 + ((ch ^ (row & 7)) << 3), Kl + cid * 8);
    }
#pragma unroll
    for (int j = 0; j < 2; ++j) {
      int cid = t + j * 256;
      int a = cid >> 3, ch = cid & 7;
      glds16(Vg + (size_t)a * 2048 + it * 64 + ((ch ^ (a & 7)) << 3), Vl + cid * 8);
    }
    __syncthreads();

    // S^T = K'-rows x Q'-rows: C row = k-local (g*4+r within mt*16), col = q-local (c)
    f32x4 s[4];
#pragma unroll
    for (int mt = 0; mt < 4; ++mt) {
      f32x4 z = f32x4{0.f, 0.f, 0.f, 0.f};
      int krow = mt * 16 + c;
#pragma unroll
      for (int fi = 0; fi < 4; ++fi) {
        bf16x8 kf = *reinterpret_cast<const bf16x8*>(
            Kl + krow * 128 + (((fi * 4 + g) ^ (c & 7)) << 3));
        z = __builtin_amdgcn_mfma_f32_16x16x32_bf16(kf, qf[fi], z, 0, 0, 0);
      }
      s[mt] = z;
    }

    // online softmax; lane owns q-row = c (16 k-vals in-lane, reduce over g via xor16/32)
    float pmax = -1e30f;
#pragma unroll
    for (int mt = 0; mt < 4; ++mt)
#pragma unroll
      for (int r = 0; r < 4; ++r) pmax = fmaxf(pmax, s[mt][r]);
    pmax = fmaxf(pmax, __shfl_xor(pmax, 16));
    pmax = fmaxf(pmax, __shfl_xor(pmax, 32));
    float mnew = fmaxf(m, pmax);
    float corr = EXP2F((m - mnew) * LOG2E);
    float rs = 0.f;
    unsigned short pu[4][4];
#pragma unroll
    for (int mt = 0; mt < 4; ++mt)
#pragma unroll
      for (int r = 0; r < 4; ++r) {
        float p = EXP2F((s[mt][r] - mnew) * LOG2E);
        rs += p;
        pu[mt][r] = f2bfu(p);
      }
    rs += __shfl_xor(rs, 16);
    rs += __shfl_xor(rs, 32);
    lsum = lsum * corr + rs;
    m = mnew;

    // write P[q=c][k = mt*16 + g*4 + r] (true-k placement; frag reads contiguous both sides)
#pragma unroll
    for (int mt = 0; mt < 4; ++mt) {
      uint2 pk;
      pk.x = (uint32_t)pu[mt][0] | ((uint32_t)pu[mt][1] << 16);
      pk.y = (uint32_t)pu[mt][2] | ((uint32_t)pu[mt][3] << 16);
      *reinterpret_cast<uint2*>(reinterpret_cast<char*>(Pw) + c * 144 + mt * 32 + g * 8) = pk;
    }

    // rescale acc (acc rows are q-local g*4+r -> fetch corr from lane owning that q)
    float corrR[4];
#pragma unroll
    for (int r = 0; r < 4; ++r) corrR[r] = __shfl(corr, g * 4 + r);
#pragma unroll
    for (int at = 0; at < 4; ++at)
#pragma unroll
      for (int r = 0; r < 4; ++r) acc[at][r] *= corrR[r];

    // PV: A = P[q][k], B = V[k][a] (from V^T rows)
    bf16x8 pf0 = *reinterpret_cast<const bf16x8*>(reinterpret_cast<char*>(Pw) + c * 144 + g * 16);
    bf16x8 pf1 = *reinterpret_cast<const bf16x8*>(reinterpret_cast<char*>(Pw) + c * 144 + 64 + g * 16);
#pragma unroll
    for (int at = 0; at < 4; ++at) {
      int arow = at * 16 + c;
      bf16x8 v0 = *reinterpret_cast<const bf16x8*>(Vl + arow * 64 + ((g ^ (c & 7)) << 3));
      bf16x8 v1 = *reinterpret_cast<const bf16x8*>(Vl + arow * 64 + (((4 + g) ^ (c & 7)) << 3));
      acc[at] = __builtin_amdgcn_mfma_f32_16x16x32_bf16(pf0, v0, acc[at], 0, 0, 0);
      acc[at] = __builtin_amdgcn_mfma_f32_16x16x32_bf16(pf1, v1, acc[at], 0, 0, 0);
    }
  }

  float lR[4];
#pragma unroll
  for (int r = 0; r < 4; ++r) lR[r] = __shfl(lsum, g * 4 + r);
  int b = bh >> 3, h = bh & 7;
  int rowg0 = b * 2048 + qb * 64 + w * 16 + g * 4;
#pragma unroll
  for (int at = 0; at < 4; ++at)
#pragma unroll
    for (int r = 0; r < 4; ++r) {
      float v = acc[at][r] / lR[r];
      ctxb[(size_t)(rowg0 + r) * 512 + h * 64 + at * 16 + c] = f2bfu(v);
    }
}

// ---------------- K3: out-proj + bias + residual -> d_out f32 (pre-LN) ----------------
__global__ __launch_bounds__(256) void k_oproj(
    const unsigned short* __restrict__ ctxb, const unsigned short* __restrict__ wt,
    const float* __restrict__ bo, const float* __restrict__ resid,
    float* __restrict__ out) {
  __shared__ __align__(16) unsigned short Al[4096];
  __shared__ __align__(16) unsigned short Bl[4096];
  int bid = blockIdx.x;
  int rb = bid >> 3, cb = bid & 7;
  const unsigned short* Ag = ctxb + (size_t)rb * 64 * 512;
  const unsigned short* Wg = wt + (size_t)5 * 262144 + (size_t)cb * 64 * 512;
  f32x4 acc[4];
#pragma unroll
  for (int i = 0; i < 4; ++i) acc[i] = f32x4{0.f, 0.f, 0.f, 0.f};
  gemm_core(Ag, Wg, Al, Bl, acc);
  int lane = threadIdx.x & 63, w = threadIdx.x >> 6, g = lane >> 4, c = lane & 15;
  int rowbase = rb * 64 + w * 16 + g * 4;
#pragma unroll
  for (int ct = 0; ct < 4; ++ct) {
    int n = cb * 64 + ct * 16 + c;
    float bv = bo[n];
#pragma unroll
    for (int r = 0; r < 4; ++r) {
      int rowg = rowbase + r;
      size_t di = (size_t)rowg * 512 + n;
      out[di] = acc[ct][r] + bv + resid[di];
    }
  }
}

// ---------------- K4: in-place LayerNorm over D=512, one row per wave ----------------
__global__ __launch_bounds__(256) void k_ln(float* __restrict__ out,
                                            const float* __restrict__ gam,
                                            const float* __restrict__ bet) {
  int row = blockIdx.x * 4 + (threadIdx.x >> 6);
  int lane = threadIdx.x & 63;
  float* x = out + (size_t)row * 512 + lane * 8;
  float4 v0 = reinterpret_cast<const float4*>(x)[0];
  float4 v1 = reinterpret_cast<const float4*>(x)[1];
  float s = v0.x + v0.y + v0.z + v0.w + v1.x + v1.y + v1.z + v1.w;
  float q = v0.x * v0.x + v0.y * v0.y + v0.z * v0.z + v0.w * v0.w +
            v1.x * v1.x + v1.y * v1.y + v1.z * v1.z + v1.w * v1.w;
#pragma unroll
  for (int d = 1; d < 64; d <<= 1) {
    s += __shfl_xor(s, d);
    q += __shfl_xor(q, d);
  }
  float mu = s * (1.0f / 512.0f);
  float var = q * (1.0f / 512.0f) - mu * mu;
  float rstd = rsqrtf(var + 1e-5f);
  float4 g0 = reinterpret_cast<const float4*>(gam + lane * 8)[0];
  float4 g1 = reinterpret_cast<const float4*>(gam + lane * 8)[1];
  float4 b0 = reinterpret_cast<const float4*>(bet + lane * 8)[0];
  float4 b1 = reinterpret_cast<const float4*>(bet + lane * 8)[1];
  v0.x = (v0.x - mu) * rstd * g0.x + b0.x;
  v0.y = (v0.y - mu) * rstd * g0.y + b0.y;
  v0.z = (v0.z - mu) * rstd * g0.z + b0.z;
  v0.w = (v0.w - mu) * rstd * g0.w + b0.w;
  v1.x = (v1.x - mu) * rstd * g1.x + b1.x;
  v1.y = (v1.y - mu) * rstd * g1.y + b1.y;
  v1.z = (v1.z - mu) * rstd * g1.z + b1.z;
  v1.w = (v1.w - mu) * rstd * g1.w + b1.w;
  reinterpret_cast<float4*>(x)[0] = v0;
  reinterpret_cast<float4*>(x)[1] = v1;
}

extern "C" void kernel_launch(void* const* d_in, const int* in_sizes, int n_in,
                              void* d_out, int out_size, void* d_ws, size_t ws_size,
                              hipStream_t stream) {
  const float* Qd  = (const float*)d_in[0];
  const float* Qt  = (const float*)d_in[1];
  const float* Kd  = (const float*)d_in[2];
  const float* Kt  = (const float*)d_in[3];
  const float* Vt  = (const float*)d_in[4];
  const float* Wqd = (const float*)d_in[5];
  const float* bqd = (const float*)d_in[6];
  const float* Wqt = (const float*)d_in[7];
  const float* bqt = (const float*)d_in[8];
  const float* Wkd = (const float*)d_in[9];
  const float* bkd = (const float*)d_in[10];
  const float* Wkt = (const float*)d_in[11];
  const float* bkt = (const float*)d_in[12];
  const float* Wvt = (const float*)d_in[13];
  const float* bvt = (const float*)d_in[14];
  const float* Wo  = (const float*)d_in[15];
  const float* bo  = (const float*)d_in[16];
  const float* lng = (const float*)d_in[17];
  const float* lnb = (const float*)d_in[18];

  char* ws = (char*)d_ws;
  unsigned short* wt   = (unsigned short*)(ws);
  unsigned short* xb   = (unsigned short*)(ws + 3145728);
  unsigned short* qws  = (unsigned short*)(ws + 45088768);
  unsigned short* kws  = (unsigned short*)(ws + 61865984);
  unsigned short* vws  = (unsigned short*)(ws + 78643200);
  unsigned short* ctxb = (unsigned short*)(ws + 87031808);
  float* out = (float*)d_out;

  k_prep_w<<<384, 256, 0, stream>>>(Wqd, Wqt, Wkd, Wkt, Wvt, Wo, wt);
  k_cvt_x<<<10240, 256, 0, stream>>>(Qd, Qt, Kd, Kt, Vt, xb);
  k_proj<<<5120, 256, 0, stream>>>(xb, wt, bqd, bqt, bkd, bkt, bvt, qws, kws, vws);
  k_attn<<<1024, 256, 0, stream>>>(qws, kws, vws, ctxb);
  k_oproj<<<1024, 256, 0, stream>>>(ctxb, wt, bo, Qd, out);
  k_ln<<<2048, 256, 0, stream>>>(out, lng, lnb);
}

// Round 3
// 188.868 us; speedup vs baseline: 1.0604x; 1.0604x over previous
//
#include <hip/hip_runtime.h>
#include <hip/hip_bf16.h>
#include <stdint.h>

// MixAttention: B=4, L=2048, D=512, H=8, A=64
// ws layout (bytes):
//  wt   @ 0        : 6*512*512*2   = 3145728   (W^T bf16, [mat][out][in])
//  qws  @ 3145728  : 32*2048*128*2 = 16777216  (Q' = [qd|qt]*0.125*log2e, [bh][l][128])
//  kws  @ 19922944 : 16777216                  (K' = [kd|kt], [bh][l][128])
//  vws  @ 36700160 : 32*64*2048*2  = 8388608   (V^T, [bh][a][l])
//  ctxb @ 45088768 : 8192*512*2    = 8388608   (attn out, [row][512])

using f32x4  = __attribute__((ext_vector_type(4))) float;
using bf16x8 = __attribute__((ext_vector_type(8))) short;

typedef __attribute__((address_space(1))) const uint32_t g_u32;
typedef __attribute__((address_space(3))) uint32_t l_u32;

#if __has_builtin(__builtin_amdgcn_exp2f)
#define EXP2F __builtin_amdgcn_exp2f
#else
#define EXP2F exp2f
#endif
#define QSCALE 0.1803368801111204f  /* 0.125 * log2(e): scores in log2 units */

__device__ __forceinline__ void glds16(const void* g, void* l) {
  __builtin_amdgcn_global_load_lds((g_u32*)g, (l_u32*)l, 16, 0, 0);
}

__device__ __forceinline__ unsigned short f2bfu(float f) {
  __hip_bfloat16 h = __float2bfloat16(f);
  union { __hip_bfloat16 h; unsigned short u; } v;
  v.h = h;
  return v.u;
}

// ---------------- K0a: W [512 in][512 out] f32 -> W^T [out][in] bf16 ----------------
__global__ __launch_bounds__(256) void k_prep_w(
    const float* __restrict__ w0, const float* __restrict__ w1,
    const float* __restrict__ w2, const float* __restrict__ w3,
    const float* __restrict__ w4, const float* __restrict__ w5,
    unsigned short* __restrict__ wt) {
  __shared__ float tile[64][68];
  const float* wsrc[6] = {w0, w1, w2, w3, w4, w5};
  int bid = blockIdx.x;
  int mat = bid >> 6, tid = bid & 63;
  int k0 = (tid >> 3) << 6, c0 = (tid & 7) << 6;
  const float* w = wsrc[mat];
  int t = threadIdx.x;
  {
    int r = t >> 2, cq = (t & 3) << 4;
    const float4* src = reinterpret_cast<const float4*>(w + (size_t)(k0 + r) * 512 + c0 + cq);
#pragma unroll
    for (int j = 0; j < 4; ++j) {
      float4 v = src[j];
      tile[r][cq + j * 4 + 0] = v.x;
      tile[r][cq + j * 4 + 1] = v.y;
      tile[r][cq + j * 4 + 2] = v.z;
      tile[r][cq + j * 4 + 3] = v.w;
    }
  }
  __syncthreads();
  {
    int cc = t >> 2, kq = (t & 3) << 4;
    union { unsigned short u[16]; uint4 v[2]; } p;
#pragma unroll
    for (int j = 0; j < 16; ++j) p.u[j] = f2bfu(tile[kq + j][cc]);
    unsigned short* dst = wt + (size_t)mat * 262144 + (size_t)(c0 + cc) * 512 + k0 + kq;
    *reinterpret_cast<uint4*>(dst)     = p.v[0];
    *reinterpret_cast<uint4*>(dst + 8) = p.v[1];
  }
}

// ---------------- K1: 5 projections, 128x128 tile, fused f32->bf16 A-staging ----------------
__global__ __launch_bounds__(256) void k_proj2(
    const float* __restrict__ x0, const float* __restrict__ x1,
    const float* __restrict__ x2, const float* __restrict__ x3,
    const float* __restrict__ x4,
    const unsigned short* __restrict__ wt,
    const float* __restrict__ b0, const float* __restrict__ b1,
    const float* __restrict__ b2, const float* __restrict__ b3,
    const float* __restrict__ b4,
    unsigned short* __restrict__ qws, unsigned short* __restrict__ kws,
    unsigned short* __restrict__ vws) {
  __shared__ __align__(16) unsigned short Abuf[8192];  // [128 r][64 k] swizzled
  __shared__ __align__(16) unsigned short Bbuf[8192];  // [128 col][64 k] swizzled
  int bid = blockIdx.x;
  int proj = bid >> 8, rem = bid & 255;
  int cb = rem >> 6, rb = rem & 63;
  const float* xs[5] = {x0, x1, x2, x3, x4};
  const float* Ag = xs[proj] + (size_t)rb * 128 * 512;
  const unsigned short* Wg = wt + (size_t)proj * 262144 + (size_t)cb * 128 * 512;
  int t = threadIdx.x;
  int lane = t & 63, w = t >> 6, wr = w >> 1, wc = w & 1, g = lane >> 4, c = lane & 15;
  f32x4 acc[4][4];
#pragma unroll
  for (int i = 0; i < 4; ++i)
#pragma unroll
    for (int j = 0; j < 4; ++j) acc[i][j] = f32x4{0.f, 0.f, 0.f, 0.f};

#pragma unroll 1
  for (int it = 0; it < 8; ++it) {
    __syncthreads();
    // B: W^T tile via async global->LDS (source pre-swizzled, dest linear)
#pragma unroll
    for (int j = 0; j < 4; ++j) {
      int cid = t + j * 256;
      int row = cid >> 3, ch = cid & 7;
      glds16(Wg + (size_t)row * 512 + it * 64 + ((ch ^ (row & 7)) << 3), Bbuf + cid * 8);
    }
    // A: f32 global -> cvt -> swizzled ds_write_b128
#pragma unroll
    for (int j = 0; j < 4; ++j) {
      int q = t + j * 256;
      int row = q >> 3, ch = q & 7;
      const float* src = Ag + (size_t)row * 512 + it * 64 + ch * 8;
      float4 a = *reinterpret_cast<const float4*>(src);
      float4 b = *reinterpret_cast<const float4*>(src + 4);
      union { unsigned short u[8]; uint4 v; } p;
      p.u[0] = f2bfu(a.x); p.u[1] = f2bfu(a.y); p.u[2] = f2bfu(a.z); p.u[3] = f2bfu(a.w);
      p.u[4] = f2bfu(b.x); p.u[5] = f2bfu(b.y); p.u[6] = f2bfu(b.z); p.u[7] = f2bfu(b.w);
      *reinterpret_cast<uint4*>(&Abuf[row * 64 + ((ch ^ (row & 7)) << 3)]) = p.v;
    }
    __syncthreads();
#pragma unroll
    for (int fi = 0; fi < 2; ++fi) {
      bf16x8 af[4], bfr[4];
#pragma unroll
      for (int mi = 0; mi < 4; ++mi) {
        int arow = wr * 64 + mi * 16 + c;
        af[mi] = *reinterpret_cast<const bf16x8*>(
            &Abuf[arow * 64 + (((fi * 4 + g) ^ (arow & 7)) << 3)]);
      }
#pragma unroll
      for (int ni = 0; ni < 4; ++ni) {
        int brow = wc * 64 + ni * 16 + c;
        bfr[ni] = *reinterpret_cast<const bf16x8*>(
            &Bbuf[brow * 64 + (((fi * 4 + g) ^ (brow & 7)) << 3)]);
      }
#pragma unroll
      for (int mi = 0; mi < 4; ++mi)
#pragma unroll
        for (int ni = 0; ni < 4; ++ni)
          acc[mi][ni] = __builtin_amdgcn_mfma_f32_16x16x32_bf16(af[mi], bfr[ni], acc[mi][ni], 0, 0, 0);
    }
  }

  const float* bias_arr[5] = {b0, b1, b2, b3, b4};
  const float* bias = bias_arr[proj];
  float scale = (proj < 2) ? QSCALE : 1.0f;
  unsigned short* qkdst = (proj < 2) ? qws : kws;
  int half = (proj & 1) ? 64 : 0;
  int h = cb * 2 + wc;
#pragma unroll
  for (int ni = 0; ni < 4; ++ni) {
    int a = ni * 16 + c;
    float bv = bias[h * 64 + a];
#pragma unroll
    for (int mi = 0; mi < 4; ++mi) {
#pragma unroll
      for (int rr = 0; rr < 4; ++rr) {
        float v = (acc[mi][ni][rr] + bv) * scale;
        unsigned short u = f2bfu(v);
        int rowg = rb * 128 + wr * 64 + mi * 16 + g * 4 + rr;
        int b = rowg >> 11, l = rowg & 2047;
        if (proj < 4) {
          qkdst[((size_t)(b * 8 + h) * 2048 + l) * 128 + half + a] = u;
        } else {
          vws[((size_t)(b * 8 + h) * 64 + a) * 2048 + l] = u;
        }
      }
    }
  }
}

// ---------------- shared GEMM core: 64x64 tile (k_oproj) ----------------
__device__ __forceinline__ void gemm_core(
    const unsigned short* Ag, const unsigned short* Wg,
    unsigned short* Al, unsigned short* Bl, f32x4 acc[4]) {
  int t = threadIdx.x;
  int lane = t & 63, w = t >> 6, g = lane >> 4, c = lane & 15;
#pragma unroll 1
  for (int it = 0; it < 8; ++it) {
    __syncthreads();
#pragma unroll
    for (int j = 0; j < 2; ++j) {
      int cid = t + j * 256;
      int row = cid >> 3, ch = cid & 7;
      glds16(Ag + (size_t)row * 512 + it * 64 + ((ch ^ (row & 7)) << 3), Al + cid * 8);
      glds16(Wg + (size_t)row * 512 + it * 64 + ((ch ^ (row & 7)) << 3), Bl + cid * 8);
    }
    __syncthreads();
#pragma unroll
    for (int fi = 0; fi < 2; ++fi) {
      int arow = w * 16 + c;
      bf16x8 af = *reinterpret_cast<const bf16x8*>(
          Al + arow * 64 + (((fi * 4 + g) ^ (arow & 7)) << 3));
#pragma unroll
      for (int ct = 0; ct < 4; ++ct) {
        int brow = ct * 16 + c;
        bf16x8 bf = *reinterpret_cast<const bf16x8*>(
            Bl + brow * 64 + (((fi * 4 + g) ^ (brow & 7)) << 3));
        acc[ct] = __builtin_amdgcn_mfma_f32_16x16x32_bf16(af, bf, acc[ct], 0, 0, 0);
      }
    }
  }
}

// ---------------- K2: flash attention, head-dim 128 QK / 64 V ----------------
__global__ __launch_bounds__(256) void k_attn(
    const unsigned short* __restrict__ qws, const unsigned short* __restrict__ kws,
    const unsigned short* __restrict__ vws, unsigned short* __restrict__ ctxb) {
  __shared__ __align__(16) unsigned short Kl[8192];     // [64 k][128 f] swizzled
  __shared__ __align__(16) unsigned short Vl[4096];     // [64 a][64 k]  swizzled
  __shared__ __align__(16) unsigned short Pl[4][1152];  // per-wave [16 q][72] (144B pitch)
  // XCD-affinity: round-robin dispatch -> XCD x owns bh in [x*4, x*4+4) (KV ~3MB, L2-fit)
  int orig = blockIdx.x;
  int xcd = orig & 7, j = orig >> 3;
  int bh = xcd * 4 + (j >> 5), qb = j & 31;
  int t = threadIdx.x;
  int w = t >> 6, lane = t & 63, g = lane >> 4, c = lane & 15;

  const unsigned short* Qg = qws + ((size_t)bh * 2048 + qb * 64 + w * 16 + c) * 128;
  bf16x8 qf[4];
#pragma unroll
  for (int fi = 0; fi < 4; ++fi)
    qf[fi] = *reinterpret_cast<const bf16x8*>(Qg + fi * 32 + g * 8);

  f32x4 acc[4];
#pragma unroll
  for (int i = 0; i < 4; ++i) acc[i] = f32x4{0.f, 0.f, 0.f, 0.f};
  float m = -1e30f, lsum = 0.f;
  const unsigned short* Kg = kws + (size_t)bh * 2048 * 128;
  const unsigned short* Vg = vws + (size_t)bh * 64 * 2048;
  unsigned short* Pw = &Pl[w][0];

#pragma unroll 1
  for (int it = 0; it < 32; ++it) {
    __syncthreads();
#pragma unroll
    for (int jj = 0; jj < 4; ++jj) {
      int cid = t + jj * 256;
      int row = cid >> 4, ch = cid & 15;
      glds16(Kg + ((size_t)it * 64 + row) * 128 + ((ch ^ (row & 7)) << 3), Kl + cid * 8);
    }
#pragma unroll
    for (int jj = 0; jj < 2; ++jj) {
      int cid = t + jj * 256;
      int a = cid >> 3, ch = cid & 7;
      glds16(Vg + (size_t)a * 2048 + it * 64 + ((ch ^ (a & 7)) << 3), Vl + cid * 8);
    }
    __syncthreads();

    // S^T = K'-rows x Q'-rows (scores already in log2 units via QSCALE)
    f32x4 s[4];
#pragma unroll
    for (int mt = 0; mt < 4; ++mt) {
      f32x4 z = f32x4{0.f, 0.f, 0.f, 0.f};
      int krow = mt * 16 + c;
#pragma unroll
      for (int fi = 0; fi < 4; ++fi) {
        bf16x8 kf = *reinterpret_cast<const bf16x8*>(
            Kl + krow * 128 + (((fi * 4 + g) ^ (c & 7)) << 3));
        z = __builtin_amdgcn_mfma_f32_16x16x32_bf16(kf, qf[fi], z, 0, 0, 0);
      }
      s[mt] = z;
    }

    // per-q-row (lane c) max over this tile: tree + cross-group shfl
    float t0 = fmaxf(fmaxf(s[0][0], s[0][1]), fmaxf(s[0][2], s[0][3]));
    float t1 = fmaxf(fmaxf(s[1][0], s[1][1]), fmaxf(s[1][2], s[1][3]));
    float t2 = fmaxf(fmaxf(s[2][0], s[2][1]), fmaxf(s[2][2], s[2][3]));
    float t3 = fmaxf(fmaxf(s[3][0], s[3][1]), fmaxf(s[3][2], s[3][3]));
    float pmax = fmaxf(fmaxf(t0, t1), fmaxf(t2, t3));
    pmax = fmaxf(pmax, __shfl_xor(pmax, 16));
    pmax = fmaxf(pmax, __shfl_xor(pmax, 32));

    // defer-max (T13, log2 units: 11.5 == 8 nats). Rescale only when max grew a lot.
    if (!__all(pmax <= m + 11.5f)) {
      float mnew = fmaxf(m, pmax);
      float corr = EXP2F(m - mnew);
      float corrR[4];
#pragma unroll
      for (int r = 0; r < 4; ++r) corrR[r] = __shfl(corr, g * 4 + r);
#pragma unroll
      for (int at = 0; at < 4; ++at)
#pragma unroll
        for (int r = 0; r < 4; ++r) acc[at][r] *= corrR[r];
      lsum *= corr;
      m = mnew;
    }

    float rs = 0.f;
    unsigned short pu[4][4];
#pragma unroll
    for (int mt = 0; mt < 4; ++mt)
#pragma unroll
      for (int r = 0; r < 4; ++r) {
        float p = EXP2F(s[mt][r] - m);
        rs += p;
        pu[mt][r] = f2bfu(p);
      }
    rs += __shfl_xor(rs, 16);
    rs += __shfl_xor(rs, 32);
    lsum += rs;

    // write P[q=c][k = mt*16 + g*4 + r]
#pragma unroll
    for (int mt = 0; mt < 4; ++mt) {
      uint2 pk;
      pk.x = (uint32_t)pu[mt][0] | ((uint32_t)pu[mt][1] << 16);
      pk.y = (uint32_t)pu[mt][2] | ((uint32_t)pu[mt][3] << 16);
      *reinterpret_cast<uint2*>(reinterpret_cast<char*>(Pw) + c * 144 + mt * 32 + g * 8) = pk;
    }

    // PV: A = P[q][k], B = V[k][a] (from V^T rows)
    bf16x8 pf0 = *reinterpret_cast<const bf16x8*>(reinterpret_cast<char*>(Pw) + c * 144 + g * 16);
    bf16x8 pf1 = *reinterpret_cast<const bf16x8*>(reinterpret_cast<char*>(Pw) + c * 144 + 64 + g * 16);
#pragma unroll
    for (int at = 0; at < 4; ++at) {
      int arow = at * 16 + c;
      bf16x8 v0 = *reinterpret_cast<const bf16x8*>(Vl + arow * 64 + ((g ^ (c & 7)) << 3));
      bf16x8 v1 = *reinterpret_cast<const bf16x8*>(Vl + arow * 64 + (((4 + g) ^ (c & 7)) << 3));
      acc[at] = __builtin_amdgcn_mfma_f32_16x16x32_bf16(pf0, v0, acc[at], 0, 0, 0);
      acc[at] = __builtin_amdgcn_mfma_f32_16x16x32_bf16(pf1, v1, acc[at], 0, 0, 0);
    }
  }

  float lR[4], rinv[4];
#pragma unroll
  for (int r = 0; r < 4; ++r) lR[r] = __shfl(lsum, g * 4 + r);
#pragma unroll
  for (int r = 0; r < 4; ++r) rinv[r] = 1.0f / lR[r];
  int b = bh >> 3, h = bh & 7;
  int rowg0 = b * 2048 + qb * 64 + w * 16 + g * 4;
#pragma unroll
  for (int at = 0; at < 4; ++at)
#pragma unroll
    for (int r = 0; r < 4; ++r) {
      float v = acc[at][r] * rinv[r];
      ctxb[(size_t)(rowg0 + r) * 512 + h * 64 + at * 16 + c] = f2bfu(v);
    }
}

// ---------------- K3: out-proj + bias + residual -> d_out f32 (pre-LN) ----------------
__global__ __launch_bounds__(256) void k_oproj(
    const unsigned short* __restrict__ ctxb, const unsigned short* __restrict__ wt,
    const float* __restrict__ bo, const float* __restrict__ resid,
    float* __restrict__ out) {
  __shared__ __align__(16) unsigned short Al[4096];
  __shared__ __align__(16) unsigned short Bl[4096];
  int bid = blockIdx.x;
  int rb = bid >> 3, cb = bid & 7;
  const unsigned short* Ag = ctxb + (size_t)rb * 64 * 512;
  const unsigned short* Wg = wt + (size_t)5 * 262144 + (size_t)cb * 64 * 512;
  f32x4 acc[4];
#pragma unroll
  for (int i = 0; i < 4; ++i) acc[i] = f32x4{0.f, 0.f, 0.f, 0.f};
  gemm_core(Ag, Wg, Al, Bl, acc);
  int lane = threadIdx.x & 63, w = threadIdx.x >> 6, g = lane >> 4, c = lane & 15;
  int rowbase = rb * 64 + w * 16 + g * 4;
#pragma unroll
  for (int ct = 0; ct < 4; ++ct) {
    int n = cb * 64 + ct * 16 + c;
    float bv = bo[n];
#pragma unroll
    for (int r = 0; r < 4; ++r) {
      int rowg = rowbase + r;
      size_t di = (size_t)rowg * 512 + n;
      out[di] = acc[ct][r] + bv + resid[di];
    }
  }
}

// ---------------- K4: in-place LayerNorm over D=512, one row per wave ----------------
__global__ __launch_bounds__(256) void k_ln(float* __restrict__ out,
                                            const float* __restrict__ gam,
                                            const float* __restrict__ bet) {
  int row = blockIdx.x * 4 + (threadIdx.x >> 6);
  int lane = threadIdx.x & 63;
  float* x = out + (size_t)row * 512 + lane * 8;
  float4 v0 = reinterpret_cast<const float4*>(x)[0];
  float4 v1 = reinterpret_cast<const float4*>(x)[1];
  float s = v0.x + v0.y + v0.z + v0.w + v1.x + v1.y + v1.z + v1.w;
  float q = v0.x * v0.x + v0.y * v0.y + v0.z * v0.z + v0.w * v0.w +
            v1.x * v1.x + v1.y * v1.y + v1.z * v1.z + v1.w * v1.w;
#pragma unroll
  for (int d = 1; d < 64; d <<= 1) {
    s += __shfl_xor(s, d);
    q += __shfl_xor(q, d);
  }
  float mu = s * (1.0f / 512.0f);
  float var = q * (1.0f / 512.0f) - mu * mu;
  float rstd = rsqrtf(var + 1e-5f);
  float4 g0 = reinterpret_cast<const float4*>(gam + lane * 8)[0];
  float4 g1 = reinterpret_cast<const float4*>(gam + lane * 8)[1];
  float4 b0 = reinterpret_cast<const float4*>(bet + lane * 8)[0];
  float4 b1 = reinterpret_cast<const float4*>(bet + lane * 8)[1];
  v0.x = (v0.x - mu) * rstd * g0.x + b0.x;
  v0.y = (v0.y - mu) * rstd * g0.y + b0.y;
  v0.z = (v0.z - mu) * rstd * g0.z + b0.z;
  v0.w = (v0.w - mu) * rstd * g0.w + b0.w;
  v1.x = (v1.x - mu) * rstd * g1.x + b1.x;
  v1.y = (v1.y - mu) * rstd * g1.y + b1.y;
  v1.z = (v1.z - mu) * rstd * g1.z + b1.z;
  v1.w = (v1.w - mu) * rstd * g1.w + b1.w;
  reinterpret_cast<float4*>(x)[0] = v0;
  reinterpret_cast<float4*>(x)[1] = v1;
}

extern "C" void kernel_launch(void* const* d_in, const int* in_sizes, int n_in,
                              void* d_out, int out_size, void* d_ws, size_t ws_size,
                              hipStream_t stream) {
  const float* Qd  = (const float*)d_in[0];
  const float* Qt  = (const float*)d_in[1];
  const float* Kd  = (const float*)d_in[2];
  const float* Kt  = (const float*)d_in[3];
  const float* Vt  = (const float*)d_in[4];
  const float* Wqd = (const float*)d_in[5];
  const float* bqd = (const float*)d_in[6];
  const float* Wqt = (const float*)d_in[7];
  const float* bqt = (const float*)d_in[8];
  const float* Wkd = (const float*)d_in[9];
  const float* bkd = (const float*)d_in[10];
  const float* Wkt = (const float*)d_in[11];
  const float* bkt = (const float*)d_in[12];
  const float* Wvt = (const float*)d_in[13];
  const float* bvt = (const float*)d_in[14];
  const float* Wo  = (const float*)d_in[15];
  const float* bo  = (const float*)d_in[16];
  const float* lng = (const float*)d_in[17];
  const float* lnb = (const float*)d_in[18];

  char* ws = (char*)d_ws;
  unsigned short* wt   = (unsigned short*)(ws);
  unsigned short* qws  = (unsigned short*)(ws + 3145728);
  unsigned short* kws  = (unsigned short*)(ws + 19922944);
  unsigned short* vws  = (unsigned short*)(ws + 36700160);
  unsigned short* ctxb = (unsigned short*)(ws + 45088768);
  float* out = (float*)d_out;

  k_prep_w<<<384, 256, 0, stream>>>(Wqd, Wqt, Wkd, Wkt, Wvt, Wo, wt);
  k_proj2<<<1280, 256, 0, stream>>>(Qd, Qt, Kd, Kt, Vt, wt,
                                    bqd, bqt, bkd, bkt, bvt, qws, kws, vws);
  k_attn<<<1024, 256, 0, stream>>>(qws, kws, vws, ctxb);
  k_oproj<<<1024, 256, 0, stream>>>(ctxb, wt, bo, Qd, out);
  k_ln<<<2048, 256, 0, stream>>>(out, lng, lnb);
}

// Round 4
// 167.599 us; speedup vs baseline: 1.1950x; 1.1269x over previous
//
#include <hip/hip_runtime.h>
#include <hip/hip_bf16.h>
#include <stdint.h>

// MixAttention: B=4, L=2048, D=512, H=8, A=64
// ws layout (bytes):
//  wt   @ 0        : 6*512*512*2   = 3145728   (W^T bf16, [mat][out][in])
//  qws  @ 3145728  : 32*2048*128*2 = 16777216  (Q' = [qd|qt]*0.125*log2e, [bh][l][128])
//  kws  @ 19922944 : 16777216                  (K' = [kd|kt], [bh][l][128])
//  vws  @ 36700160 : 32*64*2048*2  = 8388608   (V^T, [bh][a][l])
//  ctxb @ 45088768 : 8192*512*2    = 8388608   (attn out, [row][512])

using f32x4  = __attribute__((ext_vector_type(4))) float;
using bf16x8 = __attribute__((ext_vector_type(8))) short;

typedef __attribute__((address_space(1))) const uint32_t g_u32;
typedef __attribute__((address_space(3))) uint32_t l_u32;

#if __has_builtin(__builtin_amdgcn_exp2f)
#define EXP2F __builtin_amdgcn_exp2f
#else
#define EXP2F exp2f
#endif
#define QSCALE 0.1803368801111204f  /* 0.125 * log2(e): scores in log2 units */

__device__ __forceinline__ void glds16(const void* g, void* l) {
  __builtin_amdgcn_global_load_lds((g_u32*)g, (l_u32*)l, 16, 0, 0);
}

__device__ __forceinline__ unsigned short f2bfu(float f) {
  __hip_bfloat16 h = __float2bfloat16(f);
  union { __hip_bfloat16 h; unsigned short u; } v;
  v.h = h;
  return v.u;
}

// ---------------- K0a: W [512 in][512 out] f32 -> W^T [out][in] bf16 ----------------
__global__ __launch_bounds__(256) void k_prep_w(
    const float* __restrict__ w0, const float* __restrict__ w1,
    const float* __restrict__ w2, const float* __restrict__ w3,
    const float* __restrict__ w4, const float* __restrict__ w5,
    unsigned short* __restrict__ wt) {
  __shared__ float tile[64][68];
  const float* wsrc[6] = {w0, w1, w2, w3, w4, w5};
  int bid = blockIdx.x;
  int mat = bid >> 6, tid = bid & 63;
  int k0 = (tid >> 3) << 6, c0 = (tid & 7) << 6;
  const float* w = wsrc[mat];
  int t = threadIdx.x;
  {
    int r = t >> 2, cq = (t & 3) << 4;
    const float4* src = reinterpret_cast<const float4*>(w + (size_t)(k0 + r) * 512 + c0 + cq);
#pragma unroll
    for (int j = 0; j < 4; ++j) {
      float4 v = src[j];
      tile[r][cq + j * 4 + 0] = v.x;
      tile[r][cq + j * 4 + 1] = v.y;
      tile[r][cq + j * 4 + 2] = v.z;
      tile[r][cq + j * 4 + 3] = v.w;
    }
  }
  __syncthreads();
  {
    int cc = t >> 2, kq = (t & 3) << 4;
    union { unsigned short u[16]; uint4 v[2]; } p;
#pragma unroll
    for (int j = 0; j < 16; ++j) p.u[j] = f2bfu(tile[kq + j][cc]);
    unsigned short* dst = wt + (size_t)mat * 262144 + (size_t)(c0 + cc) * 512 + k0 + kq;
    *reinterpret_cast<uint4*>(dst)     = p.v[0];
    *reinterpret_cast<uint4*>(dst + 8) = p.v[1];
  }
}

// ---------------- K1: 5 projections, 128x128 tile, T14 async A-staging ----------------
__global__ __launch_bounds__(256) void k_proj2(
    const float* __restrict__ x0, const float* __restrict__ x1,
    const float* __restrict__ x2, const float* __restrict__ x3,
    const float* __restrict__ x4,
    const unsigned short* __restrict__ wt,
    const float* __restrict__ b0, const float* __restrict__ b1,
    const float* __restrict__ b2, const float* __restrict__ b3,
    const float* __restrict__ b4,
    unsigned short* __restrict__ qws, unsigned short* __restrict__ kws,
    unsigned short* __restrict__ vws) {
  __shared__ __align__(16) unsigned short Abuf[8192];  // [128 r][64 k] swizzled
  __shared__ __align__(16) unsigned short Bbuf[8192];  // [128 col][64 k] swizzled
  int bid = blockIdx.x;
  int proj = bid >> 8, rem = bid & 255;
  int cb = rem >> 6, rb = rem & 63;
  const float* xs[5] = {x0, x1, x2, x3, x4};
  const float* Ag = xs[proj] + (size_t)rb * 128 * 512;
  const unsigned short* Wg = wt + (size_t)proj * 262144 + (size_t)cb * 128 * 512;
  int t = threadIdx.x;
  int lane = t & 63, w = t >> 6, wr = w >> 1, wc = w & 1, g = lane >> 4, c = lane & 15;
  f32x4 acc[4][4];
#pragma unroll
  for (int i = 0; i < 4; ++i)
#pragma unroll
    for (int j = 0; j < 4; ++j) acc[i][j] = f32x4{0.f, 0.f, 0.f, 0.f};

  // per-thread staging coords (4 chunks of 16 f32 each)
  int srow[4], sch[4];
#pragma unroll
  for (int j = 0; j < 4; ++j) {
    int q = t + j * 256;
    srow[j] = q >> 3;
    sch[j] = q & 7;
  }
  // prologue: issue A loads for it=0
  float4 pa[4], pb[4];
#pragma unroll
  for (int j = 0; j < 4; ++j) {
    const float* src = Ag + (size_t)srow[j] * 512 + sch[j] * 8;
    pa[j] = *reinterpret_cast<const float4*>(src);
    pb[j] = *reinterpret_cast<const float4*>(src + 4);
  }

#pragma unroll 1
  for (int it = 0; it < 8; ++it) {
    __syncthreads();  // prev compute done; implicit vmcnt(0) drains prefetched A
    // A: cvt regs -> swizzled ds_write_b128
#pragma unroll
    for (int j = 0; j < 4; ++j) {
      union { unsigned short u[8]; uint4 v; } p;
      p.u[0] = f2bfu(pa[j].x); p.u[1] = f2bfu(pa[j].y);
      p.u[2] = f2bfu(pa[j].z); p.u[3] = f2bfu(pa[j].w);
      p.u[4] = f2bfu(pb[j].x); p.u[5] = f2bfu(pb[j].y);
      p.u[6] = f2bfu(pb[j].z); p.u[7] = f2bfu(pb[j].w);
      *reinterpret_cast<uint4*>(&Abuf[srow[j] * 64 + ((sch[j] ^ (srow[j] & 7)) << 3)]) = p.v;
    }
    // B: W^T tile via async global->LDS (source pre-swizzled, dest linear)
#pragma unroll
    for (int j = 0; j < 4; ++j) {
      int cid = t + j * 256;
      int row = cid >> 3, ch = cid & 7;
      glds16(Wg + (size_t)row * 512 + it * 64 + ((ch ^ (row & 7)) << 3), Bbuf + cid * 8);
    }
    __syncthreads();  // drains B glds16 + A ds_write
    // T14: issue next iteration's A loads; they fly under ds_read+MFMA below
    if (it < 7) {
#pragma unroll
      for (int j = 0; j < 4; ++j) {
        const float* src = Ag + (size_t)srow[j] * 512 + (it + 1) * 64 + sch[j] * 8;
        pa[j] = *reinterpret_cast<const float4*>(src);
        pb[j] = *reinterpret_cast<const float4*>(src + 4);
      }
    }
#pragma unroll
    for (int fi = 0; fi < 2; ++fi) {
      bf16x8 af[4], bfr[4];
#pragma unroll
      for (int mi = 0; mi < 4; ++mi) {
        int arow = wr * 64 + mi * 16 + c;
        af[mi] = *reinterpret_cast<const bf16x8*>(
            &Abuf[arow * 64 + (((fi * 4 + g) ^ (arow & 7)) << 3)]);
      }
#pragma unroll
      for (int ni = 0; ni < 4; ++ni) {
        int brow = wc * 64 + ni * 16 + c;
        bfr[ni] = *reinterpret_cast<const bf16x8*>(
            &Bbuf[brow * 64 + (((fi * 4 + g) ^ (brow & 7)) << 3)]);
      }
#pragma unroll
      for (int mi = 0; mi < 4; ++mi)
#pragma unroll
        for (int ni = 0; ni < 4; ++ni)
          acc[mi][ni] = __builtin_amdgcn_mfma_f32_16x16x32_bf16(af[mi], bfr[ni], acc[mi][ni], 0, 0, 0);
    }
  }

  const float* bias_arr[5] = {b0, b1, b2, b3, b4};
  const float* bias = bias_arr[proj];
  float scale = (proj < 2) ? QSCALE : 1.0f;
  unsigned short* qkdst = (proj < 2) ? qws : kws;
  int half = (proj & 1) ? 64 : 0;
  int h = cb * 2 + wc;
#pragma unroll
  for (int ni = 0; ni < 4; ++ni) {
    int a = ni * 16 + c;
    float bv = bias[h * 64 + a];
#pragma unroll
    for (int mi = 0; mi < 4; ++mi) {
#pragma unroll
      for (int rr = 0; rr < 4; ++rr) {
        float v = (acc[mi][ni][rr] + bv) * scale;
        unsigned short u = f2bfu(v);
        int rowg = rb * 128 + wr * 64 + mi * 16 + g * 4 + rr;
        int b = rowg >> 11, l = rowg & 2047;
        if (proj < 4) {
          qkdst[((size_t)(b * 8 + h) * 2048 + l) * 128 + half + a] = u;
        } else {
          vws[((size_t)(b * 8 + h) * 64 + a) * 2048 + l] = u;
        }
      }
    }
  }
}

// ---------------- shared GEMM core: 64x64 tile (k_oproj) ----------------
__device__ __forceinline__ void gemm_core(
    const unsigned short* Ag, const unsigned short* Wg,
    unsigned short* Al, unsigned short* Bl, f32x4 acc[4]) {
  int t = threadIdx.x;
  int lane = t & 63, w = t >> 6, g = lane >> 4, c = lane & 15;
#pragma unroll 1
  for (int it = 0; it < 8; ++it) {
    __syncthreads();
#pragma unroll
    for (int j = 0; j < 2; ++j) {
      int cid = t + j * 256;
      int row = cid >> 3, ch = cid & 7;
      glds16(Ag + (size_t)row * 512 + it * 64 + ((ch ^ (row & 7)) << 3), Al + cid * 8);
      glds16(Wg + (size_t)row * 512 + it * 64 + ((ch ^ (row & 7)) << 3), Bl + cid * 8);
    }
    __syncthreads();
#pragma unroll
    for (int fi = 0; fi < 2; ++fi) {
      int arow = w * 16 + c;
      bf16x8 af = *reinterpret_cast<const bf16x8*>(
          Al + arow * 64 + (((fi * 4 + g) ^ (arow & 7)) << 3));
#pragma unroll
      for (int ct = 0; ct < 4; ++ct) {
        int brow = ct * 16 + c;
        bf16x8 bf = *reinterpret_cast<const bf16x8*>(
            Bl + brow * 64 + (((fi * 4 + g) ^ (brow & 7)) << 3));
        acc[ct] = __builtin_amdgcn_mfma_f32_16x16x32_bf16(af, bf, acc[ct], 0, 0, 0);
      }
    }
  }
}

// ---------------- K2: flash attention, head-dim 128 QK / 64 V ----------------
__global__ __launch_bounds__(256) void k_attn(
    const unsigned short* __restrict__ qws, const unsigned short* __restrict__ kws,
    const unsigned short* __restrict__ vws, unsigned short* __restrict__ ctxb) {
  __shared__ __align__(16) unsigned short Kl[8192];     // [64 k][128 f] swizzled
  __shared__ __align__(16) unsigned short Vl[4096];     // [64 a][64 k]  swizzled
  __shared__ __align__(16) unsigned short Pl[4][1152];  // per-wave [16 q][72] (144B pitch)
  // XCD-affinity: round-robin dispatch -> XCD x owns bh in [x*4, x*4+4) (KV ~3MB, L2-fit)
  int orig = blockIdx.x;
  int xcd = orig & 7, j = orig >> 3;
  int bh = xcd * 4 + (j >> 5), qb = j & 31;
  int t = threadIdx.x;
  int w = t >> 6, lane = t & 63, g = lane >> 4, c = lane & 15;

  const unsigned short* Qg = qws + ((size_t)bh * 2048 + qb * 64 + w * 16 + c) * 128;
  bf16x8 qf[4];
#pragma unroll
  for (int fi = 0; fi < 4; ++fi)
    qf[fi] = *reinterpret_cast<const bf16x8*>(Qg + fi * 32 + g * 8);

  f32x4 acc[4];
#pragma unroll
  for (int i = 0; i < 4; ++i) acc[i] = f32x4{0.f, 0.f, 0.f, 0.f};
  float m = -1e30f, lsum = 0.f;
  const unsigned short* Kg = kws + (size_t)bh * 2048 * 128;
  const unsigned short* Vg = vws + (size_t)bh * 64 * 2048;
  unsigned short* Pw = &Pl[w][0];

#pragma unroll 1
  for (int it = 0; it < 32; ++it) {
    __syncthreads();
#pragma unroll
    for (int jj = 0; jj < 4; ++jj) {
      int cid = t + jj * 256;
      int row = cid >> 4, ch = cid & 15;
      glds16(Kg + ((size_t)it * 64 + row) * 128 + ((ch ^ (row & 7)) << 3), Kl + cid * 8);
    }
#pragma unroll
    for (int jj = 0; jj < 2; ++jj) {
      int cid = t + jj * 256;
      int a = cid >> 3, ch = cid & 7;
      glds16(Vg + (size_t)a * 2048 + it * 64 + ((ch ^ (a & 7)) << 3), Vl + cid * 8);
    }
    __syncthreads();

    // S^T = K'-rows x Q'-rows (scores already in log2 units via QSCALE)
    f32x4 s[4];
#pragma unroll
    for (int mt = 0; mt < 4; ++mt) {
      f32x4 z = f32x4{0.f, 0.f, 0.f, 0.f};
      int krow = mt * 16 + c;
#pragma unroll
      for (int fi = 0; fi < 4; ++fi) {
        bf16x8 kf = *reinterpret_cast<const bf16x8*>(
            Kl + krow * 128 + (((fi * 4 + g) ^ (c & 7)) << 3));
        z = __builtin_amdgcn_mfma_f32_16x16x32_bf16(kf, qf[fi], z, 0, 0, 0);
      }
      s[mt] = z;
    }

    // per-q-row (lane c) max over this tile: tree + cross-group shfl
    float t0 = fmaxf(fmaxf(s[0][0], s[0][1]), fmaxf(s[0][2], s[0][3]));
    float t1 = fmaxf(fmaxf(s[1][0], s[1][1]), fmaxf(s[1][2], s[1][3]));
    float t2 = fmaxf(fmaxf(s[2][0], s[2][1]), fmaxf(s[2][2], s[2][3]));
    float t3 = fmaxf(fmaxf(s[3][0], s[3][1]), fmaxf(s[3][2], s[3][3]));
    float pmax = fmaxf(fmaxf(t0, t1), fmaxf(t2, t3));
    pmax = fmaxf(pmax, __shfl_xor(pmax, 16));
    pmax = fmaxf(pmax, __shfl_xor(pmax, 32));

    // defer-max (T13, log2 units: 11.5 == 8 nats). Rescale only when max grew a lot.
    if (!__all(pmax <= m + 11.5f)) {
      float mnew = fmaxf(m, pmax);
      float corr = EXP2F(m - mnew);
      float corrR[4];
#pragma unroll
      for (int r = 0; r < 4; ++r) corrR[r] = __shfl(corr, g * 4 + r);
#pragma unroll
      for (int at = 0; at < 4; ++at)
#pragma unroll
        for (int r = 0; r < 4; ++r) acc[at][r] *= corrR[r];
      lsum *= corr;
      m = mnew;
    }

    float rs = 0.f;
    unsigned short pu[4][4];
#pragma unroll
    for (int mt = 0; mt < 4; ++mt)
#pragma unroll
      for (int r = 0; r < 4; ++r) {
        float p = EXP2F(s[mt][r] - m);
        rs += p;
        pu[mt][r] = f2bfu(p);
      }
    rs += __shfl_xor(rs, 16);
    rs += __shfl_xor(rs, 32);
    lsum += rs;

    // write P[q=c][k = mt*16 + g*4 + r]
#pragma unroll
    for (int mt = 0; mt < 4; ++mt) {
      uint2 pk;
      pk.x = (uint32_t)pu[mt][0] | ((uint32_t)pu[mt][1] << 16);
      pk.y = (uint32_t)pu[mt][2] | ((uint32_t)pu[mt][3] << 16);
      *reinterpret_cast<uint2*>(reinterpret_cast<char*>(Pw) + c * 144 + mt * 32 + g * 8) = pk;
    }

    // PV: A = P[q][k], B = V[k][a] (from V^T rows)
    bf16x8 pf0 = *reinterpret_cast<const bf16x8*>(reinterpret_cast<char*>(Pw) + c * 144 + g * 16);
    bf16x8 pf1 = *reinterpret_cast<const bf16x8*>(reinterpret_cast<char*>(Pw) + c * 144 + 64 + g * 16);
#pragma unroll
    for (int at = 0; at < 4; ++at) {
      int arow = at * 16 + c;
      bf16x8 v0 = *reinterpret_cast<const bf16x8*>(Vl + arow * 64 + ((g ^ (c & 7)) << 3));
      bf16x8 v1 = *reinterpret_cast<const bf16x8*>(Vl + arow * 64 + (((4 + g) ^ (c & 7)) << 3));
      acc[at] = __builtin_amdgcn_mfma_f32_16x16x32_bf16(pf0, v0, acc[at], 0, 0, 0);
      acc[at] = __builtin_amdgcn_mfma_f32_16x16x32_bf16(pf1, v1, acc[at], 0, 0, 0);
    }
  }

  float lR[4], rinv[4];
#pragma unroll
  for (int r = 0; r < 4; ++r) lR[r] = __shfl(lsum, g * 4 + r);
#pragma unroll
  for (int r = 0; r < 4; ++r) rinv[r] = 1.0f / lR[r];
  int b = bh >> 3, h = bh & 7;
  int rowg0 = b * 2048 + qb * 64 + w * 16 + g * 4;
#pragma unroll
  for (int at = 0; at < 4; ++at)
#pragma unroll
    for (int r = 0; r < 4; ++r) {
      float v = acc[at][r] * rinv[r];
      ctxb[(size_t)(rowg0 + r) * 512 + h * 64 + at * 16 + c] = f2bfu(v);
    }
}

// ---------------- K3: out-proj + bias + residual -> d_out f32 (pre-LN) ----------------
__global__ __launch_bounds__(256) void k_oproj(
    const unsigned short* __restrict__ ctxb, const unsigned short* __restrict__ wt,
    const float* __restrict__ bo, const float* __restrict__ resid,
    float* __restrict__ out) {
  __shared__ __align__(16) unsigned short Al[4096];
  __shared__ __align__(16) unsigned short Bl[4096];
  int bid = blockIdx.x;
  int rb = bid >> 3, cb = bid & 7;
  const unsigned short* Ag = ctxb + (size_t)rb * 64 * 512;
  const unsigned short* Wg = wt + (size_t)5 * 262144 + (size_t)cb * 64 * 512;
  f32x4 acc[4];
#pragma unroll
  for (int i = 0; i < 4; ++i) acc[i] = f32x4{0.f, 0.f, 0.f, 0.f};
  gemm_core(Ag, Wg, Al, Bl, acc);
  int lane = threadIdx.x & 63, w = threadIdx.x >> 6, g = lane >> 4, c = lane & 15;
  int rowbase = rb * 64 + w * 16 + g * 4;
#pragma unroll
  for (int ct = 0; ct < 4; ++ct) {
    int n = cb * 64 + ct * 16 + c;
    float bv = bo[n];
#pragma unroll
    for (int r = 0; r < 4; ++r) {
      int rowg = rowbase + r;
      size_t di = (size_t)rowg * 512 + n;
      out[di] = acc[ct][r] + bv + resid[di];
    }
  }
}

// ---------------- K4: in-place LayerNorm over D=512, one row per wave ----------------
__global__ __launch_bounds__(256) void k_ln(float* __restrict__ out,
                                            const float* __restrict__ gam,
                                            const float* __restrict__ bet) {
  int row = blockIdx.x * 4 + (threadIdx.x >> 6);
  int lane = threadIdx.x & 63;
  float* x = out + (size_t)row * 512 + lane * 8;
  float4 v0 = reinterpret_cast<const float4*>(x)[0];
  float4 v1 = reinterpret_cast<const float4*>(x)[1];
  float s = v0.x + v0.y + v0.z + v0.w + v1.x + v1.y + v1.z + v1.w;
  float q = v0.x * v0.x + v0.y * v0.y + v0.z * v0.z + v0.w * v0.w +
            v1.x * v1.x + v1.y * v1.y + v1.z * v1.z + v1.w * v1.w;
#pragma unroll
  for (int d = 1; d < 64; d <<= 1) {
    s += __shfl_xor(s, d);
    q += __shfl_xor(q, d);
  }
  float mu = s * (1.0f / 512.0f);
  float var = q * (1.0f / 512.0f) - mu * mu;
  float rstd = rsqrtf(var + 1e-5f);
  float4 g0 = reinterpret_cast<const float4*>(gam + lane * 8)[0];
  float4 g1 = reinterpret_cast<const float4*>(gam + lane * 8)[1];
  float4 b0 = reinterpret_cast<const float4*>(bet + lane * 8)[0];
  float4 b1 = reinterpret_cast<const float4*>(bet + lane * 8)[1];
  v0.x = (v0.x - mu) * rstd * g0.x + b0.x;
  v0.y = (v0.y - mu) * rstd * g0.y + b0.y;
  v0.z = (v0.z - mu) * rstd * g0.z + b0.z;
  v0.w = (v0.w - mu) * rstd * g0.w + b0.w;
  v1.x = (v1.x - mu) * rstd * g1.x + b1.x;
  v1.y = (v1.y - mu) * rstd * g1.y + b1.y;
  v1.z = (v1.z - mu) * rstd * g1.z + b1.z;
  v1.w = (v1.w - mu) * rstd * g1.w + b1.w;
  reinterpret_cast<float4*>(x)[0] = v0;
  reinterpret_cast<float4*>(x)[1] = v1;
}

extern "C" void kernel_launch(void* const* d_in, const int* in_sizes, int n_in,
                              void* d_out, int out_size, void* d_ws, size_t ws_size,
                              hipStream_t stream) {
  const float* Qd  = (const float*)d_in[0];
  const float* Qt  = (const float*)d_in[1];
  const float* Kd  = (const float*)d_in[2];
  const float* Kt  = (const float*)d_in[3];
  const float* Vt  = (const float*)d_in[4];
  const float* Wqd = (const float*)d_in[5];
  const float* bqd = (const float*)d_in[6];
  const float* Wqt = (const float*)d_in[7];
  const float* bqt = (const float*)d_in[8];
  const float* Wkd = (const float*)d_in[9];
  const float* bkd = (const float*)d_in[10];
  const float* Wkt = (const float*)d_in[11];
  const float* bkt = (const float*)d_in[12];
  const float* Wvt = (const float*)d_in[13];
  const float* bvt = (const float*)d_in[14];
  const float* Wo  = (const float*)d_in[15];
  const float* bo  = (const float*)d_in[16];
  const float* lng = (const float*)d_in[17];
  const float* lnb = (const float*)d_in[18];

  char* ws = (char*)d_ws;
  unsigned short* wt   = (unsigned short*)(ws);
  unsigned short* qws  = (unsigned short*)(ws + 3145728);
  unsigned short* kws  = (unsigned short*)(ws + 19922944);
  unsigned short* vws  = (unsigned short*)(ws + 36700160);
  unsigned short* ctxb = (unsigned short*)(ws + 45088768);
  float* out = (float*)d_out;

  k_prep_w<<<384, 256, 0, stream>>>(Wqd, Wqt, Wkd, Wkt, Wvt, Wo, wt);
  k_proj2<<<1280, 256, 0, stream>>>(Qd, Qt, Kd, Kt, Vt, wt,
                                    bqd, bqt, bkd, bkt, bvt, qws, kws, vws);
  k_attn<<<1024, 256, 0, stream>>>(qws, kws, vws, ctxb);
  k_oproj<<<1024, 256, 0, stream>>>(ctxb, wt, bo, Qd, out);
  k_ln<<<2048, 256, 0, stream>>>(out, lng, lnb);
}